// Round 1
// baseline (305.634 us; speedup 1.0000x reference)
//
#include <hip/hip_runtime.h>
#include <hip/hip_bf16.h>
#include <stdint.h>

// Sizes (fixed for this problem)
#define NHEADS 16
#define HDIM   64
#define DMODEL 1024
#define SEQ    2048
#define NB     2
#define MTOT   (NB*SEQ)     // 4096 rows of x
#define NTOT   (3*DMODEL)   // 3072 qkv cols
#define KTOT   DMODEL       // 1024

typedef __attribute__((ext_vector_type(8))) short          bf16x8;
typedef __attribute__((ext_vector_type(4))) float          f32x4;
typedef __attribute__((ext_vector_type(8))) unsigned short u16x8;

__device__ __forceinline__ unsigned short f2bf(float f) {
  unsigned u = __builtin_bit_cast(unsigned, f);
  u += 0x7fffu + ((u >> 16) & 1u);          // round-to-nearest-even
  return (unsigned short)(u >> 16);
}

__device__ __forceinline__ void async_copy16(void* lds, const void* g) {
  __builtin_amdgcn_global_load_lds(
      (const __attribute__((address_space(1))) unsigned int*)g,
      (__attribute__((address_space(3))) unsigned int*)lds, 16, 0, 0);
}

// ---------------------------------------------------------------- convert x
__global__ void convert_x_kernel(const float* __restrict__ x,
                                 unsigned short* __restrict__ xb) {
  int i = blockIdx.x * 256 + threadIdx.x;   // exactly MTOT*KTOT/8 threads
  const f32x4* xv = reinterpret_cast<const f32x4*>(x);
  f32x4 a = xv[2*i];
  f32x4 b = xv[2*i + 1];
  u16x8 r;
  r[0]=f2bf(a[0]); r[1]=f2bf(a[1]); r[2]=f2bf(a[2]); r[3]=f2bf(a[3]);
  r[4]=f2bf(b[0]); r[5]=f2bf(b[1]); r[6]=f2bf(b[2]); r[7]=f2bf(b[3]);
  reinterpret_cast<u16x8*>(xb)[i] = r;
}

// --------------------------------------- transpose + permute + convert W
// W: [1024][3072] f32, col j = h*192 + d*3 + c  (c in {q,k,v})
// Wt: [3072][1024] bf16, row oc = c*1024 + h*64 + d = (j%3)*1024 + j/3
__global__ void transpose_w_kernel(const float* __restrict__ W,
                                   unsigned short* __restrict__ Wt) {
  __shared__ float tile[64][65];
  int j0 = blockIdx.x * 64;   // W col tile
  int k0 = blockIdx.y * 64;   // W row tile
  int tid = threadIdx.x;      // 256
  int lr = tid >> 6;          // 0..3
  int lc = tid & 63;
  #pragma unroll
  for (int i = 0; i < 16; ++i) {
    int r = i*4 + lr;
    tile[r][lc] = W[(size_t)(k0 + r)*NTOT + j0 + lc];   // coalesced
  }
  __syncthreads();
  #pragma unroll
  for (int i = 0; i < 16; ++i) {
    int jr = i*4 + lr;
    int j  = j0 + jr;
    int oc = (j % 3)*DMODEL + (j / 3);
    Wt[(size_t)oc*KTOT + k0 + lc] = f2bf(tile[lc][jr]); // coalesced
  }
}

// ---------------------------------------------------------------- QKV GEMM
// C[m][oc] = sum_k xb[m][k]*Wt[oc][k] + b;  m=(n,t), oc=(c,h,d)
// Outputs: Q,K as [n*16+h][t][d] bf16 ; V stored transposed Vt[n*16+h][d][t]
#define BM 128
#define BN 128
#define BK 64
__launch_bounds__(256)
__global__ void qkv_gemm_kernel(const unsigned short* __restrict__ xb,
                                const unsigned short* __restrict__ wt,
                                const float* __restrict__ bqkv,
                                unsigned short* __restrict__ Qb,
                                unsigned short* __restrict__ Kb,
                                unsigned short* __restrict__ Vt) {
  __shared__ __align__(16) unsigned short As[BM*BK];
  __shared__ __align__(16) unsigned short Bs[BN*BK];
  int tid = threadIdx.x;
  int w = tid >> 6, l = tid & 63;
  int m0 = blockIdx.y * BM;
  int n0 = blockIdx.x * BN;
  int lrow = l >> 3;           // 0..7 (row within 8-row staging chunk)
  int lcol = (l & 7) * 8;      // col element base
  int wm = (w >> 1) * 64;      // wave's 64x64 quadrant
  int wn = (w & 1) * 64;
  int ln = l & 15, lg = l >> 4;

  f32x4 acc[4][4];
  const f32x4 zero4 = {0.f, 0.f, 0.f, 0.f};
  #pragma unroll
  for (int i = 0; i < 4; ++i)
    #pragma unroll
    for (int j = 0; j < 4; ++j) acc[i][j] = zero4;

  for (int kt = 0; kt < KTOT/BK; ++kt) {
    int k0 = kt * BK;
    #pragma unroll
    for (int i = 0; i < 4; ++i) {           // each wave stages 32 rows of A and B
      int rbase = w*32 + i*8;
      async_copy16(&As[rbase*BK], &xb[(size_t)(m0 + rbase + lrow)*KTOT + k0 + lcol]);
      async_copy16(&Bs[rbase*BK], &wt[(size_t)(n0 + rbase + lrow)*KTOT + k0 + lcol]);
    }
    asm volatile("s_waitcnt vmcnt(0)" ::: "memory");
    __syncthreads();
    #pragma unroll
    for (int ks = 0; ks < 2; ++ks) {
      bf16x8 af[4], bfr[4];
      #pragma unroll
      for (int mi = 0; mi < 4; ++mi)
        af[mi] = *reinterpret_cast<const bf16x8*>(&As[(wm + mi*16 + ln)*BK + ks*32 + lg*8]);
      #pragma unroll
      for (int ni = 0; ni < 4; ++ni)
        bfr[ni] = *reinterpret_cast<const bf16x8*>(&Bs[(wn + ni*16 + ln)*BK + ks*32 + lg*8]);
      #pragma unroll
      for (int mi = 0; mi < 4; ++mi)
        #pragma unroll
        for (int ni = 0; ni < 4; ++ni)
          acc[mi][ni] = __builtin_amdgcn_mfma_f32_16x16x32_bf16(af[mi], bfr[ni], acc[mi][ni], 0, 0, 0);
    }
    __syncthreads();
  }

  // Epilogue: route to Q / K / Vt with bias. c is block-uniform (128 | 1024).
  int r4 = lg * 4;
  #pragma unroll
  for (int mi = 0; mi < 4; ++mi) {
    #pragma unroll
    for (int ni = 0; ni < 4; ++ni) {
      int nc = n0 + wn + ni*16 + ln;
      int c  = nc >> 10;
      int hd = nc & 1023;
      int h = hd >> 6, d = hd & 63;
      float bias = bqkv[hd*3 + c];
      #pragma unroll
      for (int j = 0; j < 4; ++j) {
        int m = m0 + wm + mi*16 + r4 + j;
        int n = m >> 11, t = m & 2047;
        unsigned short val = f2bf(acc[mi][ni][j] + bias);
        size_t nh = (size_t)(n*NHEADS + h);
        if (c == 0)      Qb[((nh*SEQ + t) << 6) + d] = val;
        else if (c == 1) Kb[((nh*SEQ + t) << 6) + d] = val;
        else             Vt[((nh*HDIM + d) << 11) + t] = val;
      }
    }
  }
}

// ---------------------------------------------------------------- attention
// Flash-style. Block = 4 waves; wave handles 16 q rows; KV tile = 64 keys.
// Mask is mathematically a no-op (query-axis constant shift inside softmax).
__launch_bounds__(256)
__global__ void attn_kernel(const unsigned short* __restrict__ Qb,
                            const unsigned short* __restrict__ Kb,
                            const unsigned short* __restrict__ Vt,
                            float* __restrict__ out) {
  __shared__ __align__(16) unsigned short P_lds[4][16][72];  // per-wave, +8 pad
  int tid = threadIdx.x;
  int w = tid >> 6, l = tid & 63;
  int lg = l >> 4, ln = l & 15;
  int bh = blockIdx.y;                    // n*16 + h
  int q0 = blockIdx.x * 64 + w * 16;
  const unsigned short* Qh = Qb + (size_t)bh * SEQ * HDIM;
  const unsigned short* Kh = Kb + (size_t)bh * SEQ * HDIM;
  const unsigned short* Vh = Vt + (size_t)bh * HDIM * SEQ;

  // Q fragments (row = q0+ln, k-range lg*8 within each 32-chunk)
  bf16x8 aq[2];
  #pragma unroll
  for (int kk = 0; kk < 2; ++kk)
    aq[kk] = *reinterpret_cast<const bf16x8*>(&Qh[(size_t)(q0 + ln)*HDIM + kk*32 + lg*8]);

  const f32x4 zero4 = {0.f, 0.f, 0.f, 0.f};
  f32x4 o[4]; 
  #pragma unroll
  for (int dc = 0; dc < 4; ++dc) o[dc] = zero4;
  float mrow[4] = {-INFINITY, -INFINITY, -INFINITY, -INFINITY};
  float lrow[4] = {0.f, 0.f, 0.f, 0.f};

  for (int kv = 0; kv < SEQ/64; ++kv) {
    int key0 = kv * 64;
    // ---- S = (Q K^T) * 0.125 ; S[q=(lg*4+j)][key=kc*16+ln] per lane
    f32x4 s[4];
    #pragma unroll
    for (int kc = 0; kc < 4; ++kc) {
      bf16x8 bk0 = *reinterpret_cast<const bf16x8*>(&Kh[(size_t)(key0 + kc*16 + ln)*HDIM + lg*8]);
      bf16x8 bk1 = *reinterpret_cast<const bf16x8*>(&Kh[(size_t)(key0 + kc*16 + ln)*HDIM + 32 + lg*8]);
      f32x4 t0 = __builtin_amdgcn_mfma_f32_16x16x32_bf16(aq[0], bk0, zero4, 0, 0, 0);
      s[kc]    = __builtin_amdgcn_mfma_f32_16x16x32_bf16(aq[1], bk1, t0,    0, 0, 0);
    }
    #pragma unroll
    for (int kc = 0; kc < 4; ++kc)
      #pragma unroll
      for (int j = 0; j < 4; ++j) s[kc][j] *= 0.125f;

    // ---- online softmax stats (rows live across 16-lane groups)
    float scl[4];
    #pragma unroll
    for (int j = 0; j < 4; ++j) {
      float v = fmaxf(fmaxf(s[0][j], s[1][j]), fmaxf(s[2][j], s[3][j]));
      v = fmaxf(v, __shfl_xor(v, 1));
      v = fmaxf(v, __shfl_xor(v, 2));
      v = fmaxf(v, __shfl_xor(v, 4));
      v = fmaxf(v, __shfl_xor(v, 8));
      float mn = fmaxf(mrow[j], v);
      scl[j] = __expf(mrow[j] - mn);
      mrow[j] = mn;
    }
    // ---- P = exp(S - m), stash to LDS for the A-operand transpose
    #pragma unroll
    for (int kc = 0; kc < 4; ++kc)
      #pragma unroll
      for (int j = 0; j < 4; ++j) {
        float p = __expf(s[kc][j] - mrow[j]);
        s[kc][j] = p;
        P_lds[w][lg*4 + j][kc*16 + ln] = f2bf(p);
      }
    #pragma unroll
    for (int j = 0; j < 4; ++j) {
      float v = (s[0][j] + s[1][j]) + (s[2][j] + s[3][j]);
      v += __shfl_xor(v, 1);
      v += __shfl_xor(v, 2);
      v += __shfl_xor(v, 4);
      v += __shfl_xor(v, 8);
      lrow[j] = lrow[j]*scl[j] + v;
    }
    // ---- rescale accumulator
    #pragma unroll
    for (int dc = 0; dc < 4; ++dc)
      #pragma unroll
      for (int j = 0; j < 4; ++j) o[dc][j] *= scl[j];

    // ---- PV: A = P (from LDS), B = Vt rows (contiguous in key)
    bf16x8 pa[2];
    #pragma unroll
    for (int ks = 0; ks < 2; ++ks)
      pa[ks] = *reinterpret_cast<const bf16x8*>(&P_lds[w][ln][ks*32 + lg*8]);
    #pragma unroll
    for (int dc = 0; dc < 4; ++dc) {
      bf16x8 bv0 = *reinterpret_cast<const bf16x8*>(&Vh[(size_t)(dc*16 + ln)*SEQ + key0 + lg*8]);
      bf16x8 bv1 = *reinterpret_cast<const bf16x8*>(&Vh[(size_t)(dc*16 + ln)*SEQ + key0 + 32 + lg*8]);
      o[dc] = __builtin_amdgcn_mfma_f32_16x16x32_bf16(pa[0], bv0, o[dc], 0, 0, 0);
      o[dc] = __builtin_amdgcn_mfma_f32_16x16x32_bf16(pa[1], bv1, o[dc], 0, 0, 0);
    }
  }

  // ---- normalize + write f32 output [N][T][H*D]
  int n = bh >> 4, h = bh & 15;
  #pragma unroll
  for (int dc = 0; dc < 4; ++dc)
    #pragma unroll
    for (int j = 0; j < 4; ++j) {
      int q = q0 + lg*4 + j;
      out[((size_t)(n*SEQ + q))*DMODEL + h*HDIM + dc*16 + ln] = o[dc][j] / lrow[j];
    }
}

// ---------------------------------------------------------------- launcher
extern "C" void kernel_launch(void* const* d_in, const int* in_sizes, int n_in,
                              void* d_out, int out_size, void* d_ws, size_t ws_size,
                              hipStream_t stream) {
  const float* x    = (const float*)d_in[0];
  // d_in[1] = mask: constant shift along query axis inside softmax -> no-op
  const float* Wq   = (const float*)d_in[2];
  const float* bq   = (const float*)d_in[3];
  float* out = (float*)d_out;

  unsigned short* xb = (unsigned short*)d_ws;                    // [4096][1024]
  unsigned short* wt = xb + (size_t)MTOT*KTOT;                   // [3072][1024]
  unsigned short* Qb = wt + (size_t)NTOT*KTOT;                   // [32][2048][64]
  unsigned short* Kb = Qb + (size_t)NB*NHEADS*SEQ*HDIM;          // [32][2048][64]
  unsigned short* Vt = Kb + (size_t)NB*NHEADS*SEQ*HDIM;          // [32][64][2048]

  convert_x_kernel<<<(MTOT*KTOT/8)/256, 256, 0, stream>>>(x, xb);
  transpose_w_kernel<<<dim3(NTOT/64, KTOT/64), 256, 0, stream>>>(Wq, wt);
  qkv_gemm_kernel<<<dim3(NTOT/BN, MTOT/BM), 256, 0, stream>>>(xb, wt, bq, Qb, Kb, Vt);
  attn_kernel<<<dim3(SEQ/64, NB*NHEADS), 256, 0, stream>>>(Qb, Kb, Vt, out);
}

// Round 4
// 304.413 us; speedup vs baseline: 1.0040x; 1.0040x over previous
//
#include <hip/hip_runtime.h>
#include <hip/hip_bf16.h>
#include <stdint.h>

// Sizes (fixed for this problem)
#define NHEADS 16
#define HDIM   64
#define DMODEL 1024
#define SEQ    2048
#define NB     2
#define MTOT   (NB*SEQ)     // 4096 rows of x
#define NTOT   (3*DMODEL)   // 3072 qkv cols
#define KTOT   DMODEL       // 1024

// fold (1/8)*log2(e) into Q so softmax runs in exp2 domain
#define QSCALE 0.18033688011112042f

typedef __attribute__((ext_vector_type(8)))  short          bf16x8;
typedef __attribute__((ext_vector_type(4)))  float          f32x4;
typedef __attribute__((ext_vector_type(8)))  unsigned short u16x8;

__device__ __forceinline__ unsigned short f2bf(float f) {
  unsigned u = __builtin_bit_cast(unsigned, f);
  u += 0x7fffu + ((u >> 16) & 1u);          // round-to-nearest-even
  return (unsigned short)(u >> 16);
}

__device__ __forceinline__ void async_copy16(void* lds, const void* g) {
  __builtin_amdgcn_global_load_lds(
      (const __attribute__((address_space(1))) unsigned int*)g,
      (__attribute__((address_space(3))) unsigned int*)lds, 16, 0, 0);
}

// ---------------------------------------------------------------- convert x
__global__ void convert_x_kernel(const float* __restrict__ x,
                                 unsigned short* __restrict__ xb) {
  int i = blockIdx.x * 256 + threadIdx.x;
  const f32x4* xv = reinterpret_cast<const f32x4*>(x);
  f32x4 a = xv[2*i];
  f32x4 b = xv[2*i + 1];
  u16x8 r;
  r[0]=f2bf(a[0]); r[1]=f2bf(a[1]); r[2]=f2bf(a[2]); r[3]=f2bf(a[3]);
  r[4]=f2bf(b[0]); r[5]=f2bf(b[1]); r[6]=f2bf(b[2]); r[7]=f2bf(b[3]);
  reinterpret_cast<u16x8*>(xb)[i] = r;
}

// --------------------------------------- transpose + permute + convert W
__global__ void transpose_w_kernel(const float* __restrict__ W,
                                   unsigned short* __restrict__ Wt) {
  __shared__ float tile[64][65];
  int j0 = blockIdx.x * 64;
  int k0 = blockIdx.y * 64;
  int tid = threadIdx.x;
  int lr = tid >> 6;
  int lc = tid & 63;
  #pragma unroll
  for (int i = 0; i < 16; ++i) {
    int r = i*4 + lr;
    tile[r][lc] = W[(size_t)(k0 + r)*NTOT + j0 + lc];
  }
  __syncthreads();
  #pragma unroll
  for (int i = 0; i < 16; ++i) {
    int jr = i*4 + lr;
    int j  = j0 + jr;
    int oc = (j % 3)*DMODEL + (j / 3);
    Wt[(size_t)oc*KTOT + k0 + lc] = f2bf(tile[lc][jr]);
  }
}

// ---------------------------------------------------------------- QKV GEMM
#define BM 128
#define BN 128
#define BK 64
__launch_bounds__(256)
__global__ void qkv_gemm_kernel(const unsigned short* __restrict__ xb,
                                const unsigned short* __restrict__ wt,
                                const float* __restrict__ bqkv,
                                unsigned short* __restrict__ Qb,
                                unsigned short* __restrict__ Kb,
                                unsigned short* __restrict__ Vt) {
  __shared__ __align__(16) unsigned short As[BM*BK];
  __shared__ __align__(16) unsigned short Bs[BN*BK];
  int tid = threadIdx.x;
  int w = tid >> 6, l = tid & 63;
  int m0 = blockIdx.y * BM;
  int n0 = blockIdx.x * BN;
  int lrow = l >> 3;
  int lcol = (l & 7) * 8;
  int wm = (w >> 1) * 64;
  int wn = (w & 1) * 64;
  int ln = l & 15, lg = l >> 4;

  f32x4 acc[4][4];
  const f32x4 zero4 = {0.f, 0.f, 0.f, 0.f};
  #pragma unroll
  for (int i = 0; i < 4; ++i)
    #pragma unroll
    for (int j = 0; j < 4; ++j) acc[i][j] = zero4;

  for (int kt = 0; kt < KTOT/BK; ++kt) {
    int k0 = kt * BK;
    #pragma unroll
    for (int i = 0; i < 4; ++i) {
      int rbase = w*32 + i*8;
      async_copy16(&As[rbase*BK], &xb[(size_t)(m0 + rbase + lrow)*KTOT + k0 + lcol]);
      async_copy16(&Bs[rbase*BK], &wt[(size_t)(n0 + rbase + lrow)*KTOT + k0 + lcol]);
    }
    asm volatile("s_waitcnt vmcnt(0)" ::: "memory");
    __syncthreads();
    #pragma unroll
    for (int ks = 0; ks < 2; ++ks) {
      bf16x8 af[4], bfr[4];
      #pragma unroll
      for (int mi = 0; mi < 4; ++mi)
        af[mi] = *reinterpret_cast<const bf16x8*>(&As[(wm + mi*16 + ln)*BK + ks*32 + lg*8]);
      #pragma unroll
      for (int ni = 0; ni < 4; ++ni)
        bfr[ni] = *reinterpret_cast<const bf16x8*>(&Bs[(wn + ni*16 + ln)*BK + ks*32 + lg*8]);
      #pragma unroll
      for (int mi = 0; mi < 4; ++mi)
        #pragma unroll
        for (int ni = 0; ni < 4; ++ni)
          acc[mi][ni] = __builtin_amdgcn_mfma_f32_16x16x32_bf16(af[mi], bfr[ni], acc[mi][ni], 0, 0, 0);
    }
    __syncthreads();
  }

  int r4 = lg * 4;
  #pragma unroll
  for (int mi = 0; mi < 4; ++mi) {
    #pragma unroll
    for (int ni = 0; ni < 4; ++ni) {
      int nc = n0 + wn + ni*16 + ln;
      int c  = nc >> 10;
      int hd = nc & 1023;
      int h = hd >> 6, d = hd & 63;
      float bias = bqkv[hd*3 + c];
      float qs = (c == 0) ? QSCALE : 1.0f;   // fold softmax scale into Q
      #pragma unroll
      for (int j = 0; j < 4; ++j) {
        int m = m0 + wm + mi*16 + r4 + j;
        int n = m >> 11, t = m & 2047;
        unsigned short val = f2bf((acc[mi][ni][j] + bias) * qs);
        size_t nh = (size_t)(n*NHEADS + h);
        if (c == 0)      Qb[((nh*SEQ + t) << 6) + d] = val;
        else if (c == 1) Kb[((nh*SEQ + t) << 6) + d] = val;
        else             Vt[((nh*HDIM + d) << 11) + t] = val;
      }
    }
  }
}

// ---------------------------------------------------------------- attention
// Swapped flash attention built ONLY from 16x16x32 MFMA pieces whose A/B/C/D
// lane maps were hardware-validated by the round-1 pass:
//   A-frag: row=l&15,  k=8*(l>>4)+j   B-frag: col=l&15, k=8*(l>>4)+j
//   C/D   : col=l&15,  row=4*(l>>4)+reg
// S^T = mfma(A=K, B=Q): lane holds q=l&15, keys 4*(l>>4)+r  -> softmax =
// in-lane tree + shfl_xor(16) + shfl_xor(32). P goes through per-wave LDS
// (f2bf pair packing), PV = mfma(A=V^T from global, B=P^T from LDS).
#define PROW 72   // padded P/obuf row (72 bf16 / 72 f32); 144B keeps 16B align
__launch_bounds__(256)
__global__ void attn_kernel(const unsigned short* __restrict__ Qb,
                            const unsigned short* __restrict__ Kb,
                            const unsigned short* __restrict__ Vt,
                            float* __restrict__ out) {
  __shared__ __align__(16) unsigned char smem[4 * 16 * PROW * 4]; // 18432 B
  int tid = threadIdx.x;
  int w = tid >> 6, l = tid & 63;
  int ln = l & 15, lg = l >> 4;

  // per-wave LDS regions (P and obuf alias; never live simultaneously)
  unsigned short* Pw  = (unsigned short*)(smem + w * 16 * PROW * 4);
  float*          obw = (float*)         (smem + w * 16 * PROW * 4);

  // XCD clustering: 1024 blocks, 8 XCDs -> each XCD owns 4 heads
  int fid  = blockIdx.x;
  int xcd  = fid & 7, idx = fid >> 3;
  int bh   = xcd * 4 + (idx >> 5);      // 0..31
  int qblk = idx & 31;                  // 0..31
  int q0   = qblk * 64 + w * 16;

  const unsigned short* Qh = Qb + (size_t)bh * SEQ * HDIM;
  const unsigned short* Kh = Kb + (size_t)bh * SEQ * HDIM;
  const unsigned short* Vh = Vt + (size_t)bh * HDIM * SEQ;

  // Q B-fragments (col = q = ln), d-windows dw=0,1
  bf16x8 qf[2];
  #pragma unroll
  for (int dw = 0; dw < 2; ++dw)
    qf[dw] = *reinterpret_cast<const bf16x8*>(&Qh[(size_t)(q0 + ln)*HDIM + dw*32 + lg*8]);

  const f32x4 zero4 = {0.f, 0.f, 0.f, 0.f};
  f32x4 o[4];
  #pragma unroll
  for (int db = 0; db < 4; ++db) o[db] = zero4;
  float mrow = -INFINITY, lrow = 0.f;

  for (int kv = 0; kv < SEQ/64; ++kv) {
    int key0 = kv * 64;

    // ---- S^T: 4 key-blocks x 2 d-windows
    f32x4 s[4];
    #pragma unroll
    for (int kb = 0; kb < 4; ++kb) {
      bf16x8 k0 = *reinterpret_cast<const bf16x8*>(
          &Kh[(size_t)(key0 + kb*16 + ln)*HDIM + lg*8]);
      bf16x8 k1 = *reinterpret_cast<const bf16x8*>(
          &Kh[(size_t)(key0 + kb*16 + ln)*HDIM + 32 + lg*8]);
      f32x4 t0 = __builtin_amdgcn_mfma_f32_16x16x32_bf16(k0, qf[0], zero4, 0, 0, 0);
      s[kb]    = __builtin_amdgcn_mfma_f32_16x16x32_bf16(k1, qf[1], t0,    0, 0, 0);
    }

    // ---- V A-fragments (independent of softmax): issue loads now
    bf16x8 vfr[2][4];
    #pragma unroll
    for (int kw = 0; kw < 2; ++kw)
      #pragma unroll
      for (int db = 0; db < 4; ++db)
        vfr[kw][db] = *reinterpret_cast<const bf16x8*>(
            &Vh[(size_t)(db*16 + ln)*SEQ + key0 + kw*32 + lg*8]);

    // ---- row max: in-lane tree + cross-lane (row q=ln spans lg groups)
    float a0 = fmaxf(fmaxf(s[0][0], s[0][1]), fmaxf(s[0][2], s[0][3]));
    float a1 = fmaxf(fmaxf(s[1][0], s[1][1]), fmaxf(s[1][2], s[1][3]));
    float a2 = fmaxf(fmaxf(s[2][0], s[2][1]), fmaxf(s[2][2], s[2][3]));
    float a3 = fmaxf(fmaxf(s[3][0], s[3][1]), fmaxf(s[3][2], s[3][3]));
    float pm = fmaxf(fmaxf(a0, a1), fmaxf(a2, a3));
    pm = fmaxf(pm, __shfl_xor(pm, 16));
    pm = fmaxf(pm, __shfl_xor(pm, 32));

    // ---- always-rescale online update (exp2 domain)
    float mn  = fmaxf(mrow, pm);
    float scl = __builtin_amdgcn_exp2f(mrow - mn);
    mrow = mn;
    lrow *= scl;
    #pragma unroll
    for (int db = 0; db < 4; ++db)
      #pragma unroll
      for (int r = 0; r < 4; ++r) o[db][r] *= scl;

    // ---- P = exp2(S - m); row sum
    #pragma unroll
    for (int kb = 0; kb < 4; ++kb)
      #pragma unroll
      for (int r = 0; r < 4; ++r)
        s[kb][r] = __builtin_amdgcn_exp2f(s[kb][r] - mn);
    float b0 = (s[0][0] + s[0][1]) + (s[0][2] + s[0][3]);
    float b1 = (s[1][0] + s[1][1]) + (s[1][2] + s[1][3]);
    float b2 = (s[2][0] + s[2][1]) + (s[2][2] + s[2][3]);
    float b3 = (s[3][0] + s[3][1]) + (s[3][2] + s[3][3]);
    float ts = (b0 + b1) + (b2 + b3);
    ts += __shfl_xor(ts, 16);
    ts += __shfl_xor(ts, 32);
    lrow += ts;

    // ---- P -> LDS, row q=ln, col key (validated f2bf pair packing)
    #pragma unroll
    for (int kb = 0; kb < 4; ++kb) {
      unsigned pa = (unsigned)f2bf(s[kb][0]) | ((unsigned)f2bf(s[kb][1]) << 16);
      unsigned pb = (unsigned)f2bf(s[kb][2]) | ((unsigned)f2bf(s[kb][3]) << 16);
      *reinterpret_cast<unsigned*>(&Pw[ln*PROW + kb*16 + 4*lg])     = pa;
      *reinterpret_cast<unsigned*>(&Pw[ln*PROW + kb*16 + 4*lg + 2]) = pb;
    }

    // ---- PV: A = V^T chunk, B = P^T from LDS (canonical B-frag read)
    #pragma unroll
    for (int kw = 0; kw < 2; ++kw) {
      bf16x8 pb = *reinterpret_cast<const bf16x8*>(&Pw[ln*PROW + kw*32 + lg*8]);
      #pragma unroll
      for (int db = 0; db < 4; ++db)
        o[db] = __builtin_amdgcn_mfma_f32_16x16x32_bf16(vfr[kw][db], pb, o[db], 0, 0, 0);
    }
  }

  // ---- normalize + transpose via LDS + coalesced store
  float inv = 1.f / lrow;
  #pragma unroll
  for (int db = 0; db < 4; ++db)
    #pragma unroll
    for (int r = 0; r < 4; ++r)
      obw[ln*PROW + db*16 + 4*lg + r] = o[db][r] * inv;
  asm volatile("s_waitcnt lgkmcnt(0)" ::: "memory");
  int n = bh >> 4, h = bh & 15;
  #pragma unroll
  for (int p = 0; p < 4; ++p) {
    int q = p*4 + lg;
    f32x4 vv = *reinterpret_cast<const f32x4*>(&obw[q*PROW + ln*4]);
    *reinterpret_cast<f32x4*>(
        &out[((size_t)(n*SEQ + q0 + q))*DMODEL + h*HDIM + ln*4]) = vv;
  }
}

// ---------------------------------------------------------------- launcher
extern "C" void kernel_launch(void* const* d_in, const int* in_sizes, int n_in,
                              void* d_out, int out_size, void* d_ws, size_t ws_size,
                              hipStream_t stream) {
  const float* x    = (const float*)d_in[0];
  // d_in[1] = mask: constant shift along query axis inside softmax -> no-op
  const float* Wq   = (const float*)d_in[2];
  const float* bq   = (const float*)d_in[3];
  float* out = (float*)d_out;

  unsigned short* xb = (unsigned short*)d_ws;                    // [4096][1024]
  unsigned short* wt = xb + (size_t)MTOT*KTOT;                   // [3072][1024]
  unsigned short* Qb = wt + (size_t)NTOT*KTOT;                   // [32][2048][64]
  unsigned short* Kb = Qb + (size_t)NB*NHEADS*SEQ*HDIM;          // [32][2048][64]
  unsigned short* Vt = Kb + (size_t)NB*NHEADS*SEQ*HDIM;          // [32][64][2048]

  convert_x_kernel<<<(MTOT*KTOT/8)/256, 256, 0, stream>>>(x, xb);
  transpose_w_kernel<<<dim3(NTOT/64, KTOT/64), 256, 0, stream>>>(Wq, wt);
  qkv_gemm_kernel<<<dim3(NTOT/BN, MTOT/BM), 256, 0, stream>>>(xb, wt, bq, Qb, Kb, Vt);
  attn_kernel<<<1024, 256, 0, stream>>>(Qb, Kb, Vt, out);
}